// Round 2
// baseline (109.854 us; speedup 1.0000x reference)
//
#include <hip/hip_runtime.h>
#include <math.h>

// Geometry (fixed by setup_inputs):
//   carrier: (B=8, T=32768, 2*FD=258) float32, flat = 67,633,152 elements
//   real view x[b, s, f, c] -> flat = b*BSTRIDE + s*ROW + f*2 + c
#define T_LEN   32768
#define ROW     258
#define BATCH   8
#define BSTRIDE (T_LEN * ROW)            // 8,454,144 floats per batch
#define NFLOAT  (BATCH * BSTRIDE)        // 67,633,152 floats total
#define N4      (NFLOAT / 4)             // 16,908,288 float4s
#define FIX_LIM (20 * ROW)               // 5160: all fixup positions have (flat % BSTRIDE) < this

// Fused copy + inject/blend. Every float4 is copied; the (rare) float4s whose
// within-batch offset falls below FIX_LIM get the per-element blend applied by
// the SAME thread that copies them -> single dispatch, no write race.
__global__ __launch_bounds__(256)
void arith_copy_blend(const float4* __restrict__ x4,
                      float4* __restrict__ o4,
                      const float* __restrict__ blend_p,
                      const int* __restrict__ src_p)
{
    const int stride = gridDim.x * blockDim.x;
    for (int i = blockIdx.x * blockDim.x + threadIdx.x; i < N4; i += stride) {
        float4 v = x4[i];
        const unsigned flat = (unsigned)i << 2;
        const unsigned b    = flat / (unsigned)BSTRIDE;   // magic-mul (const divisor)
        const int      rem  = (int)(flat - b * (unsigned)BSTRIDE);

        if (__builtin_expect(rem < FIX_LIM, 0)) {
            const int   src = *src_p;
            const float bl  = 1.0f / (1.0f + expf(-(*blend_p)));   // sigmoid
            const float omb = 1.0f - bl;
            float* e = reinterpret_cast<float*>(&v);
            #pragma unroll
            for (int k = 0; k < 4; ++k) {
                const int j  = rem + k;        // within-batch flat offset
                const int s  = j / ROW;        // register index along T
                const int f2 = j - s * ROW;    // 2*freq + comp (f2<2 <=> freq bin 0)
                bool  fix = false;
                float sym = 0.0f;
                if (src == 0) {                               // START
                    fix = (s < 20);                           // all freq bins
                } else if (src >= 1 && src <= 10) {           // DIGIT
                    if (s >= 2 && s <= 11 && f2 < 2) {
                        fix = true;
                        sym = (s == 2 + (src - 1) % 10 && f2 == 0) ? 1.0f : 0.0f;
                    }
                } else if (src == 11 || src == 12) {          // PLUS / MINUS
                    if (s == 1 && f2 < 2) {
                        fix = true;
                        sym = (f2 == 0) ? ((src == 11) ? 1.0f : -1.0f) : 0.0f;
                    }
                } else if (src == 13) {                       // EQUALS
                    if (((s >= 14 && s <= 16) || s == 1 ||
                         (s >= 2 && s <= 11)) && f2 < 2)
                        fix = true;                           // sym = 0
                }
                if (fix) e[k] = omb * e[k] + bl * sym;
            }
        }
        o4[i] = v;
    }
}

extern "C" void kernel_launch(void* const* d_in, const int* in_sizes, int n_in,
                              void* d_out, int out_size, void* d_ws, size_t ws_size,
                              hipStream_t stream) {
    const float4* x4      = (const float4*)d_in[0];  // carrier_freq_flat
    const float*  blend_p = (const float*)d_in[1];   // symbolic_blend (scalar)
    const int*    src_p   = (const int*)d_in[2];     // src_token
    // d_in[3] = tgt_token: only participates in the None-check, unused here.
    float4* o4 = (float4*)d_out;

    // Memory-bound streaming kernel: ~2048 blocks, grid-stride (G11).
    arith_copy_blend<<<2048, 256, 0, stream>>>(x4, o4, blend_p, src_p);
}